// Round 11
// baseline (398.095 us; speedup 1.0000x reference)
//
#include <hip/hip_runtime.h>
#include <float.h>

// Problem constants: x (2,128,64,64) fp32, w (256,256) fp32, b (256,) fp32
// out (2,256,64,64) fp32. K=9 nearest neighbors on normalized features.
constexpr int CB = 2;      // batch
constexpr int CC = 128;    // channels
constexpr int CN = 4096;   // points (64*64)
constexpr int CO2 = 512;   // P(256) + Q(256) packed weight columns
constexpr int NSPLIT = 8;  // knn col-splits

// ---- workspace layout (float offsets) ----
// bf16x3 planes (6MB) OVERLAY the Q region (8MB): planes are consumed by
// knn_kernel BEFORE pq_kernel writes Q (same stream, serialized).
constexpr size_t OFF_XN = 0;                                  // [B][C][N] normalized x (fp32)
constexpr size_t OFF_SQ = OFF_XN + (size_t)CB * CC * CN;      // [B][N] sum(xn^2)
constexpr size_t OFF_RN = OFF_SQ + (size_t)CB * CN;           // [B][N] norm
constexpr size_t OFF_WT = OFF_RN + (size_t)CB * CN;           // [C][512] (W1-W2 | W2)^T
constexpr size_t OFF_Q  = OFF_WT + (size_t)CC * CO2;          // [B][N][256] Q (fp32)
constexpr size_t OFF_PV = OFF_Q  + (size_t)CB * CN * 256;     // [B][N][8][9] vals
constexpr size_t OFF_PJ = OFF_PV + (size_t)CB * CN * 72;      // [B][N][8][9] idx
constexpr size_t OFF_NN = OFF_PJ + (size_t)CB * CN * 72;      // [B][N][9] final idx

typedef __attribute__((ext_vector_type(8))) short bf16x8;
typedef __attribute__((ext_vector_type(4))) float f32x4;

__device__ __forceinline__ unsigned short f2bf(float f) {
    unsigned int u = __float_as_uint(f);
    unsigned int r = (u + 0x7FFFu + ((u >> 16) & 1u)) >> 16;   // round-nearest-even
    return (unsigned short)r;
}
__device__ __forceinline__ float bf2f(unsigned short h) {
    return __uint_as_float(((unsigned int)h) << 16);
}

// top-9 sorted-desc insert; comparator matches jax.lax.top_k tie-break.
__device__ __forceinline__ void topk_insert(float (&sv)[9], int (&sj)[9], float v, int jg) {
    if ((v > sv[8]) || (v == sv[8] && jg < sj[8])) {
        bool bb[9];
#pragma unroll
        for (int k = 0; k < 9; ++k) bb[k] = (v > sv[k]) || (v == sv[k] && jg < sj[k]);
#pragma unroll
        for (int k = 8; k >= 1; --k) {
            sv[k] = bb[k - 1] ? sv[k - 1] : (bb[k] ? v : sv[k]);
            sj[k] = bb[k - 1] ? sj[k - 1] : (bb[k] ? jg : sj[k]);
        }
        sv[0] = bb[0] ? v : sv[0];
        sj[0] = bb[0] ? jg : sj[0];
    }
}

// ---- Kernel A: normalize + emit bf16x3 TRANSPOSED planes x{h,m,l}T[b][n][c] ----
__global__ __launch_bounds__(256) void prep_kernel(const float* __restrict__ x,
                                                   float* __restrict__ xn,
                                                   float* __restrict__ sqv,
                                                   float* __restrict__ rnv,
                                                   unsigned short* __restrict__ xh,
                                                   unsigned short* __restrict__ xm,
                                                   unsigned short* __restrict__ xl) {
    __shared__ float XT[128][65];              // +1 pad: column reads conflict-free
    __shared__ float red[4][64];
    __shared__ float invl[64];
    const int b = blockIdx.y, n0 = blockIdx.x * 64;
    const int tid = threadIdx.x;
    const int nl = tid & 63, c0 = tid >> 6;
#pragma unroll 4
    for (int cc = 0; cc < 32; ++cc) {
        int c = cc * 4 + c0;
        XT[c][nl] = x[((size_t)(b * 128 + c)) * 4096 + n0 + nl];
    }
    __syncthreads();
    {
        float acc = 0.f;
#pragma unroll 4
        for (int cc = 0; cc < 32; ++cc) { float v = XT[c0 * 32 + cc][nl]; acc += v * v; }
        red[c0][nl] = acc;
    }
    __syncthreads();
    if (tid < 64) {
        float ss = red[0][tid] + red[1][tid] + red[2][tid] + red[3][tid] + 1e-12f;
        float sr = sqrtf(ss);
        invl[tid] = 1.0f / sr;
        rnv[b * 4096 + n0 + tid] = sr;
    }
    __syncthreads();
    {
        float acc = 0.f;
        float iv = invl[nl];
#pragma unroll 4
        for (int cc = 0; cc < 32; ++cc) {
            int c = cc * 4 + c0;
            float v = XT[c][nl] * iv;
            xn[((size_t)(b * 128 + c)) * 4096 + n0 + nl] = v;
            XT[c][nl] = v;                     // keep normalized value for pass 3
            acc += v * v;
        }
        red[c0][nl] = acc;
    }
    __syncthreads();
    if (tid < 64) {
        sqv[b * 4096 + n0 + tid] = red[0][tid] + red[1][tid] + red[2][tid] + red[3][tid];
    }
    __syncthreads();
    // pass 3: bf16x3 split, transposed [n][c] layout
    {
        const int n = tid & 63, cq = tid >> 6;     // thread: one n, 32 c's
        unsigned short hs[32], ms[32], ls[32];
#pragma unroll
        for (int cc = 0; cc < 32; ++cc) {
            float v = XT[cq * 32 + cc][n];
            unsigned short h = f2bf(v);  float hf = bf2f(h);
            float r1 = v - hf;
            unsigned short m = f2bf(r1); float mf = bf2f(m);
            unsigned short l = f2bf(r1 - mf);
            hs[cc] = h; ms[cc] = m; ls[cc] = l;
        }
        const size_t base = ((size_t)(b * 4096 + n0 + n)) * 128 + cq * 32;
#pragma unroll
        for (int q2 = 0; q2 < 4; ++q2) {
            *(float4*)&xh[base + q2 * 8] = *(const float4*)&hs[q2 * 8];
            *(float4*)&xm[base + q2 * 8] = *(const float4*)&ms[q2 * 8];
            *(float4*)&xl[base + q2 * 8] = *(const float4*)&ls[q2 * 8];
        }
    }
}

// ---- Kernel W: WT[c][o] = (o<256) ? w[o][c]-w[o][128+c] : w[o-256][128+c] ----
__global__ __launch_bounds__(256) void wprep_kernel(const float* __restrict__ w,
                                                    float* __restrict__ wt) {
    int id = blockIdx.x * 256 + threadIdx.x;   // 65536 = 128*512
    int c = id >> 9, o = id & 511;
    float v;
    if (o < 256) v = w[o * 256 + c] - w[o * 256 + 128 + c];
    else         v = w[(o - 256) * 256 + 128 + c];
    wt[c * 512 + o] = v;
}

// ---- Kernel B v11: MFMA bf16x3 Gram, REGISTER-RESIDENT scan (operand swap) ----
// mfma(J, I): D row = J-row ((lane>>4)*4+reg), D col = I-row (lane&15)  [m89 +
// r10-validated orientation]. Lane owns ONE i-row; its 16 j-scores/tile live in
// acc regs -> top-9 scan entirely in registers. Score s = 2*inner - sq_j (the
// -sq_i shift is constant per i-row: order AND tie structure preserved, and
// cross-split merge shares i). ZERO barriers + ZERO LDS in the main loop; waves
// free-run (r10: 72% stall from 24 barriers/block + lockstep load waits).
// LDS only for the final merge: 4608 floats exactly (r9 lesson).
// acc = 4 x f32x4 = 16 floats (the only allocator-safe size: r3/r4/r8).
__global__ __launch_bounds__(256, 2) void knn_kernel(const unsigned short* __restrict__ xh,
                                                     const unsigned short* __restrict__ xm,
                                                     const unsigned short* __restrict__ xl,
                                                     const float* __restrict__ sqv,
                                                     float* __restrict__ pv,
                                                     int* __restrict__ pj) {
    __shared__ float lds[4608];                // 18,432 B: MV[256][9] + MJ[256][9]
    float* MV = lds;
    int*   MJ = (int*)(lds + 2304);

    const int b  = blockIdx.z;
    const int i0 = blockIdx.y * 64;
    const int js = blockIdx.x;                 // cols js*512 .. +511
    const int tid = threadIdx.x;
    const int lane = tid & 63, w = tid >> 6;
    const int l15 = lane & 15, l4 = lane >> 4;

    // I-frag (2nd operand): this lane's i-row = i0 + w*16 + l15
    const size_t irow = ((size_t)(b * 4096 + i0 + w * 16 + l15)) * 128;
    float sv[9]; int sj[9];
#pragma unroll
    for (int k = 0; k < 9; ++k) { sv[k] = -FLT_MAX; sj[k] = 0x7fffffff; }

    for (int t = 0; t < 8; ++t) {
        const int jt = js * 512 + t * 64;
        // J-frag base (1st operand): row jt + y*16 + l15, plane pointers
        const size_t jb = ((size_t)(b * 4096 + jt + l15)) * 128;
        f32x4 a0 = {0.f, 0.f, 0.f, 0.f}, a1 = a0, a2 = a0, a3 = a0;

#pragma unroll
        for (int ch = 0; ch < 4; ++ch) {       // K chunks of 32; no barriers
            const int ko = ch * 32 + l4 * 8;
            const bf16x8 ih = *(const bf16x8*)(xh + irow + ko);
            const bf16x8 im = *(const bf16x8*)(xm + irow + ko);
            const bf16x8 il = *(const bf16x8*)(xl + irow + ko);
#define DO_Y(ACC, Y)                                                          \
            {                                                                 \
                const bf16x8 jh = *(const bf16x8*)(xh + jb + (Y) * 2048 + ko);\
                const bf16x8 jm = *(const bf16x8*)(xm + jb + (Y) * 2048 + ko);\
                const bf16x8 jl = *(const bf16x8*)(xl + jb + (Y) * 2048 + ko);\
                ACC = __builtin_amdgcn_mfma_f32_16x16x32_bf16(jh, ih, ACC, 0, 0, 0); \
                ACC = __builtin_amdgcn_mfma_f32_16x16x32_bf16(jh, im, ACC, 0, 0, 0); \
                ACC = __builtin_amdgcn_mfma_f32_16x16x32_bf16(jm, ih, ACC, 0, 0, 0); \
                ACC = __builtin_amdgcn_mfma_f32_16x16x32_bf16(jm, im, ACC, 0, 0, 0); \
                ACC = __builtin_amdgcn_mfma_f32_16x16x32_bf16(jh, il, ACC, 0, 0, 0); \
                ACC = __builtin_amdgcn_mfma_f32_16x16x32_bf16(jl, ih, ACC, 0, 0, 0); \
            }
            DO_Y(a0, 0) DO_Y(a1, 1) DO_Y(a2, 2) DO_Y(a3, 3)
#undef DO_Y
        }
        // register-resident scan: lane's j = jt + y*16 + l4*4 + r
#define SCAN_Y(ACC, Y)                                                        \
        {                                                                     \
            const float4 sq4 = *(const float4*)&sqv[b * 4096 + jt + (Y) * 16 + l4 * 4]; \
            topk_insert(sv, sj, 2.0f * ACC[0] - sq4.x, jt + (Y) * 16 + l4 * 4 + 0); \
            topk_insert(sv, sj, 2.0f * ACC[1] - sq4.y, jt + (Y) * 16 + l4 * 4 + 1); \
            topk_insert(sv, sj, 2.0f * ACC[2] - sq4.z, jt + (Y) * 16 + l4 * 4 + 2); \
            topk_insert(sv, sj, 2.0f * ACC[3] - sq4.w, jt + (Y) * 16 + l4 * 4 + 3); \
        }
        SCAN_Y(a0, 0) SCAN_Y(a1, 1) SCAN_Y(a2, 2) SCAN_Y(a3, 3)
#undef SCAN_Y
    }
    // merge: i-row (w*16 + l15) has 4 lists, at lanes {l15, l15+16, +32, +48}
#pragma unroll
    for (int k = 0; k < 9; ++k) { MV[tid * 9 + k] = sv[k]; MJ[tid * 9 + k] = sj[k]; }
    __syncthreads();
    if (tid < 64) {                            // i = i0 + tid  (wsrc = tid>>4, r = tid&15)
        float mv[9]; int mj[9];
#pragma unroll
        for (int k = 0; k < 9; ++k) { mv[k] = -FLT_MAX; mj[k] = 0x7fffffff; }
        const int wsrc = tid >> 4, r = tid & 15;
        for (int q2 = 0; q2 < 4; ++q2) {
            const int src = wsrc * 64 + q2 * 16 + r;
            for (int k = 0; k < 9; ++k)
                topk_insert(mv, mj, MV[src * 9 + k], MJ[src * 9 + k]);
        }
        const int base = ((b * 4096 + i0 + tid) * NSPLIT + js) * 9;
#pragma unroll
        for (int k = 0; k < 9; ++k) { pv[base + k] = mv[k]; pj[base + k] = mj[k]; }
    }
}

// ---- Kernel M: merge 8 split-lists -> final 9 indices per row ----
__global__ __launch_bounds__(256) void merge_kernel(const float* __restrict__ pv,
                                                    const int* __restrict__ pj,
                                                    int* __restrict__ nn) {
    int t = blockIdx.x * 256 + threadIdx.x;
    float sv[9]; int sj[9];
#pragma unroll
    for (int k = 0; k < 9; ++k) { sv[k] = -FLT_MAX; sj[k] = 0x7fffffff; }
    int base = t * (NSPLIT * 9);
    for (int s = 0; s < NSPLIT * 9; ++s) topk_insert(sv, sj, pv[base + s], pj[base + s]);
#pragma unroll
    for (int k = 0; k < 9; ++k) nn[t * 9 + k] = sj[k];
}

// ---- Kernel C: P/Q GEMM (fp32, unchanged) ----
__global__ __launch_bounds__(256, 2) void pq_kernel(const float* __restrict__ xn,
                                                    const float* __restrict__ wt,
                                                    const float* __restrict__ rnv,
                                                    float* __restrict__ q,
                                                    float* __restrict__ out) {
    __shared__ float Xs[128][64];
    __shared__ float Ws[128][64];
    const int b = blockIdx.z;
    const int n0 = blockIdx.x * 64;
    const int o0 = blockIdx.y * 64;
    const int tid = threadIdx.x;
    {
        const int c4 = tid >> 4, j4 = (tid & 15) * 4;
#pragma unroll
        for (int cc = 0; cc < 8; ++cc) {
            int c = cc * 16 + c4;
            *(float4*)&Xs[c][j4] = *(const float4*)&xn[((size_t)(b * 128 + c)) * 4096 + n0 + j4];
            *(float4*)&Ws[c][j4] = *(const float4*)&wt[c * 512 + o0 + j4];
        }
    }
    __syncthreads();
    const int tx = tid & 15, ty = tid >> 4;
    float acc[4][4];
#pragma unroll
    for (int i = 0; i < 4; ++i)
#pragma unroll
        for (int j = 0; j < 4; ++j) acc[i][j] = 0.f;
#pragma unroll 4
    for (int c = 0; c < 128; ++c) {
        const float4 av = *(const float4*)&Xs[c][ty * 4];
        const float4 bv = *(const float4*)&Ws[c][tx * 4];
        const float ar[4] = {av.x, av.y, av.z, av.w};
        const float br[4] = {bv.x, bv.y, bv.z, bv.w};
#pragma unroll
        for (int i = 0; i < 4; ++i)
#pragma unroll
            for (int j = 0; j < 4; ++j) acc[i][j] = fmaf(ar[i], br[j], acc[i][j]);
    }
    const float4 rv = *(const float4*)&rnv[b * 4096 + n0 + ty * 4];
    if (o0 < 256) {
#pragma unroll
        for (int j = 0; j < 4; ++j) {
            float4 v = make_float4(acc[0][j] * rv.x, acc[1][j] * rv.y,
                                   acc[2][j] * rv.z, acc[3][j] * rv.w);
            *(float4*)&out[((size_t)(b * 256 + o0 + tx * 4 + j)) * 4096 + n0 + ty * 4] = v;
        }
    } else {
        const float rr[4] = {rv.x, rv.y, rv.z, rv.w};
#pragma unroll
        for (int i = 0; i < 4; ++i) {
            float4 v = make_float4(acc[i][0] * rr[i], acc[i][1] * rr[i],
                                   acc[i][2] * rr[i], acc[i][3] * rr[i]);
            *(float4*)&q[((size_t)(b * 4096 + n0 + ty * 4 + i)) * 256 + (o0 - 256) + tx * 4] = v;
        }
    }
}

// ---- Kernel D: out = relu(P(out) + bias + max_k Q[nn]) in place (unchanged) ----
__global__ __launch_bounds__(256) void gather_kernel(const float* __restrict__ q,
                                                     const int* __restrict__ nn,
                                                     const float* __restrict__ bias,
                                                     float* __restrict__ out) {
    __shared__ int idx[32][9];
    const int b = blockIdx.y, n0 = blockIdx.x * 32;
    const int tid = threadIdx.x;
    for (int t = tid; t < 288; t += 256) {
        int pt = t / 9, k = t - pt * 9;
        idx[pt][k] = nn[(b * 4096 + n0 + pt) * 9 + k];
    }
    __syncthreads();
    const float bv = bias[tid];
    const size_t orow = ((size_t)(b * 256 + tid)) * 4096 + n0;
    float pvals[32];
#pragma unroll
    for (int u = 0; u < 8; ++u)
        *(float4*)&pvals[u * 4] = *(const float4*)&out[orow + u * 4];
    float val[32];
#pragma unroll
    for (int pt = 0; pt < 32; ++pt) {
        float m = -FLT_MAX;
#pragma unroll
        for (int k = 0; k < 9; ++k) {
            int j = idx[pt][k] & 4095;
            m = fmaxf(m, q[((size_t)(b * 4096 + j)) * 256 + tid]);
        }
        float vv = pvals[pt] + bv + m;
        val[pt] = vv > 0.f ? vv : 0.f;
    }
#pragma unroll
    for (int u = 0; u < 8; ++u) {
        float4 v = make_float4(val[u * 4], val[u * 4 + 1], val[u * 4 + 2], val[u * 4 + 3]);
        *(float4*)&out[orow + u * 4] = v;
    }
}

extern "C" void kernel_launch(void* const* d_in, const int* in_sizes, int n_in,
                              void* d_out, int out_size, void* d_ws, size_t ws_size,
                              hipStream_t stream) {
    const float* x    = (const float*)d_in[0];
    const float* w    = (const float*)d_in[1];
    const float* bias = (const float*)d_in[2];
    float* ws = (float*)d_ws;
    float* xn = ws + OFF_XN;
    float* sq = ws + OFF_SQ;
    float* rn = ws + OFF_RN;
    float* wt = ws + OFF_WT;
    float* q  = ws + OFF_Q;
    unsigned short* xh = (unsigned short*)(ws + OFF_Q);        // planes overlay Q
    unsigned short* xm = xh + (size_t)CB * CN * CC;
    unsigned short* xl = xm + (size_t)CB * CN * CC;
    float* pv = ws + OFF_PV;
    int*   pj = (int*)(ws + OFF_PJ);
    int*   nn = (int*)(ws + OFF_NN);
    float* out = (float*)d_out;

    prep_kernel  <<<dim3(64, 2),    256, 0, stream>>>(x, xn, sq, rn, xh, xm, xl);
    wprep_kernel <<<dim3(256),      256, 0, stream>>>(w, wt);
    knn_kernel   <<<dim3(8, 64, 2), 256, 0, stream>>>(xh, xm, xl, sq, pv, pj);
    merge_kernel <<<dim3(32),       256, 0, stream>>>(pv, pj, nn);
    pq_kernel    <<<dim3(64, 8, 2), 256, 0, stream>>>(xn, wt, rn, q, out);
    gather_kernel<<<dim3(128, 2),   256, 0, stream>>>(q, nn, bias, out);
}

// Round 12
// 342.914 us; speedup vs baseline: 1.1609x; 1.1609x over previous
//
#include <hip/hip_runtime.h>
#include <float.h>

// Problem constants: x (2,128,64,64) fp32, w (256,256) fp32, b (256,) fp32
// out (2,256,64,64) fp32. K=9 nearest neighbors on normalized features.
constexpr int CB = 2;      // batch
constexpr int CC = 128;    // channels
constexpr int CN = 4096;   // points (64*64)
constexpr int CO2 = 512;   // P(256) + Q(256) packed weight columns
constexpr int NSPLIT = 8;  // knn col-splits

// ---- workspace layout (float offsets) ----
// bf16x3 planes (6MB) OVERLAY the Q region (8MB): planes are consumed by
// knn_kernel BEFORE pq_kernel writes Q (same stream, serialized).
constexpr size_t OFF_XN = 0;                                  // [B][C][N] normalized x (fp32)
constexpr size_t OFF_SQ = OFF_XN + (size_t)CB * CC * CN;      // [B][N] sum(xn^2)
constexpr size_t OFF_RN = OFF_SQ + (size_t)CB * CN;           // [B][N] norm
constexpr size_t OFF_WT = OFF_RN + (size_t)CB * CN;           // [C][512] (W1-W2 | W2)^T
constexpr size_t OFF_Q  = OFF_WT + (size_t)CC * CO2;          // [B][N][256] Q (fp32)
constexpr size_t OFF_PV = OFF_Q  + (size_t)CB * CN * 256;     // [B][N][8][9] vals
constexpr size_t OFF_PJ = OFF_PV + (size_t)CB * CN * 72;      // [B][N][8][9] idx
constexpr size_t OFF_NN = OFF_PJ + (size_t)CB * CN * 72;      // [B][N][9] final idx

typedef __attribute__((ext_vector_type(8))) short bf16x8;
typedef __attribute__((ext_vector_type(4))) float f32x4;

__device__ __forceinline__ unsigned short f2bf(float f) {
    unsigned int u = __float_as_uint(f);
    unsigned int r = (u + 0x7FFFu + ((u >> 16) & 1u)) >> 16;   // round-nearest-even
    return (unsigned short)r;
}
__device__ __forceinline__ float bf2f(unsigned short h) {
    return __uint_as_float(((unsigned int)h) << 16);
}

// top-9 sorted-desc insert; comparator matches jax.lax.top_k tie-break.
// Result = min-9 under a total order -> independent of scan order.
__device__ __forceinline__ void topk_insert(float (&sv)[9], int (&sj)[9], float v, int jg) {
    if ((v > sv[8]) || (v == sv[8] && jg < sj[8])) {
        bool bb[9];
#pragma unroll
        for (int k = 0; k < 9; ++k) bb[k] = (v > sv[k]) || (v == sv[k] && jg < sj[k]);
#pragma unroll
        for (int k = 8; k >= 1; --k) {
            sv[k] = bb[k - 1] ? sv[k - 1] : (bb[k] ? v : sv[k]);
            sj[k] = bb[k - 1] ? sj[k - 1] : (bb[k] ? jg : sj[k]);
        }
        sv[0] = bb[0] ? v : sv[0];
        sj[0] = bb[0] ? jg : sj[0];
    }
}

// ---- Kernel A: normalize + emit bf16x3 TRANSPOSED planes x{h,m,l}T[b][n][c] ----
__global__ __launch_bounds__(256) void prep_kernel(const float* __restrict__ x,
                                                   float* __restrict__ xn,
                                                   float* __restrict__ sqv,
                                                   float* __restrict__ rnv,
                                                   unsigned short* __restrict__ xh,
                                                   unsigned short* __restrict__ xm,
                                                   unsigned short* __restrict__ xl) {
    __shared__ float XT[128][65];              // +1 pad: column reads conflict-free
    __shared__ float red[4][64];
    __shared__ float invl[64];
    const int b = blockIdx.y, n0 = blockIdx.x * 64;
    const int tid = threadIdx.x;
    const int nl = tid & 63, c0 = tid >> 6;
#pragma unroll 4
    for (int cc = 0; cc < 32; ++cc) {
        int c = cc * 4 + c0;
        XT[c][nl] = x[((size_t)(b * 128 + c)) * 4096 + n0 + nl];
    }
    __syncthreads();
    {
        float acc = 0.f;
#pragma unroll 4
        for (int cc = 0; cc < 32; ++cc) { float v = XT[c0 * 32 + cc][nl]; acc += v * v; }
        red[c0][nl] = acc;
    }
    __syncthreads();
    if (tid < 64) {
        float ss = red[0][tid] + red[1][tid] + red[2][tid] + red[3][tid] + 1e-12f;
        float sr = sqrtf(ss);
        invl[tid] = 1.0f / sr;
        rnv[b * 4096 + n0 + tid] = sr;
    }
    __syncthreads();
    {
        float acc = 0.f;
        float iv = invl[nl];
#pragma unroll 4
        for (int cc = 0; cc < 32; ++cc) {
            int c = cc * 4 + c0;
            float v = XT[c][nl] * iv;
            xn[((size_t)(b * 128 + c)) * 4096 + n0 + nl] = v;
            XT[c][nl] = v;                     // keep normalized value for pass 3
            acc += v * v;
        }
        red[c0][nl] = acc;
    }
    __syncthreads();
    if (tid < 64) {
        sqv[b * 4096 + n0 + tid] = red[0][tid] + red[1][tid] + red[2][tid] + red[3][tid];
    }
    __syncthreads();
    // pass 3: bf16x3 split, transposed [n][c] layout
    {
        const int n = tid & 63, cq = tid >> 6;     // thread: one n, 32 c's
        unsigned short hs[32], ms[32], ls[32];
#pragma unroll
        for (int cc = 0; cc < 32; ++cc) {
            float v = XT[cq * 32 + cc][n];
            unsigned short h = f2bf(v);  float hf = bf2f(h);
            float r1 = v - hf;
            unsigned short m = f2bf(r1); float mf = bf2f(m);
            unsigned short l = f2bf(r1 - mf);
            hs[cc] = h; ms[cc] = m; ls[cc] = l;
        }
        const size_t base = ((size_t)(b * 4096 + n0 + n)) * 128 + cq * 32;
#pragma unroll
        for (int q2 = 0; q2 < 4; ++q2) {
            *(float4*)&xh[base + q2 * 8] = *(const float4*)&hs[q2 * 8];
            *(float4*)&xm[base + q2 * 8] = *(const float4*)&ms[q2 * 8];
            *(float4*)&xl[base + q2 * 8] = *(const float4*)&ls[q2 * 8];
        }
    }
}

// ---- Kernel W: WT[c][o] = (o<256) ? w[o][c]-w[o][128+c] : w[o-256][128+c] ----
__global__ __launch_bounds__(256) void wprep_kernel(const float* __restrict__ w,
                                                    float* __restrict__ wt) {
    int id = blockIdx.x * 256 + threadIdx.x;   // 65536 = 128*512
    int c = id >> 9, o = id & 511;
    float v;
    if (o < 256) v = w[o * 256 + c] - w[o * 256 + 128 + c];
    else         v = w[(o - 256) * 256 + 128 + c];
    wt[c * 512 + o] = v;
}

// ---- Kernel B v12: MFMA bf16x3 Gram, register-resident scan ----
// = v11 + two latency fixes (selection bit-identical):
//  (a) __launch_bounds__(256,4): v11 live state is 76 VGPR + 16 acc = 92 <= 128
//      cap -> 4 blocks/CU (v11 ran at 2; 72% of cycles were un-hidden L2/L3
//      latency at FETCH ~25MB, 105 GB/s). Grid 1024 = exactly 4/CU.
//  (b) per-wave tile stagger t_eff = (t + 2w) & 7: the 4 waves touch 4
//      DIFFERENT J-tiles at any instant (v11: lockstep 4x-redundant bursts).
//      Top-9 under a total order is scan-order-independent.
// mfma(J, I): D row = J-row ((lane>>4)*4+reg), D col = I-row (lane&15).
// Score s = 2*inner - sq_j (the -sq_i shift is per-i constant; order and ties
// preserved; merge shares i). Zero barriers / zero LDS in the main loop.
__global__ __launch_bounds__(256, 4) void knn_kernel(const unsigned short* __restrict__ xh,
                                                     const unsigned short* __restrict__ xm,
                                                     const unsigned short* __restrict__ xl,
                                                     const float* __restrict__ sqv,
                                                     float* __restrict__ pv,
                                                     int* __restrict__ pj) {
    __shared__ float lds[4608];                // 18,432 B: MV[256][9] + MJ[256][9]
    float* MV = lds;
    int*   MJ = (int*)(lds + 2304);

    const int b  = blockIdx.z;
    const int i0 = blockIdx.y * 64;
    const int js = blockIdx.x;                 // cols js*512 .. +511
    const int tid = threadIdx.x;
    const int lane = tid & 63, w = tid >> 6;
    const int l15 = lane & 15, l4 = lane >> 4;

    // I-frag (2nd operand): this lane's i-row = i0 + w*16 + l15
    const size_t irow = ((size_t)(b * 4096 + i0 + w * 16 + l15)) * 128;
    float sv[9]; int sj[9];
#pragma unroll
    for (int k = 0; k < 9; ++k) { sv[k] = -FLT_MAX; sj[k] = 0x7fffffff; }

    for (int tt = 0; tt < 8; ++tt) {
        const int t = (tt + w * 2) & 7;        // stagger: waves desynchronized
        const int jt = js * 512 + t * 64;
        // J-frag base (1st operand): row jt + y*16 + l15, plane pointers
        const size_t jb = ((size_t)(b * 4096 + jt + l15)) * 128;
        f32x4 a0 = {0.f, 0.f, 0.f, 0.f}, a1 = a0, a2 = a0, a3 = a0;

#pragma unroll
        for (int ch = 0; ch < 4; ++ch) {       // K chunks of 32; no barriers
            const int ko = ch * 32 + l4 * 8;
            const bf16x8 ih = *(const bf16x8*)(xh + irow + ko);
            const bf16x8 im = *(const bf16x8*)(xm + irow + ko);
            const bf16x8 il = *(const bf16x8*)(xl + irow + ko);
#define DO_Y(ACC, Y)                                                          \
            {                                                                 \
                const bf16x8 jh = *(const bf16x8*)(xh + jb + (Y) * 2048 + ko);\
                const bf16x8 jm = *(const bf16x8*)(xm + jb + (Y) * 2048 + ko);\
                const bf16x8 jl = *(const bf16x8*)(xl + jb + (Y) * 2048 + ko);\
                ACC = __builtin_amdgcn_mfma_f32_16x16x32_bf16(jh, ih, ACC, 0, 0, 0); \
                ACC = __builtin_amdgcn_mfma_f32_16x16x32_bf16(jh, im, ACC, 0, 0, 0); \
                ACC = __builtin_amdgcn_mfma_f32_16x16x32_bf16(jm, ih, ACC, 0, 0, 0); \
                ACC = __builtin_amdgcn_mfma_f32_16x16x32_bf16(jm, im, ACC, 0, 0, 0); \
                ACC = __builtin_amdgcn_mfma_f32_16x16x32_bf16(jh, il, ACC, 0, 0, 0); \
                ACC = __builtin_amdgcn_mfma_f32_16x16x32_bf16(jl, ih, ACC, 0, 0, 0); \
            }
            DO_Y(a0, 0) DO_Y(a1, 1) DO_Y(a2, 2) DO_Y(a3, 3)
#undef DO_Y
        }
        // register-resident scan: lane's j = jt + y*16 + l4*4 + r
#define SCAN_Y(ACC, Y)                                                        \
        {                                                                     \
            const float4 sq4 = *(const float4*)&sqv[b * 4096 + jt + (Y) * 16 + l4 * 4]; \
            topk_insert(sv, sj, 2.0f * ACC[0] - sq4.x, jt + (Y) * 16 + l4 * 4 + 0); \
            topk_insert(sv, sj, 2.0f * ACC[1] - sq4.y, jt + (Y) * 16 + l4 * 4 + 1); \
            topk_insert(sv, sj, 2.0f * ACC[2] - sq4.z, jt + (Y) * 16 + l4 * 4 + 2); \
            topk_insert(sv, sj, 2.0f * ACC[3] - sq4.w, jt + (Y) * 16 + l4 * 4 + 3); \
        }
        SCAN_Y(a0, 0) SCAN_Y(a1, 1) SCAN_Y(a2, 2) SCAN_Y(a3, 3)
#undef SCAN_Y
    }
    // merge: i-row (w*16 + l15) has 4 lists, at lanes {l15, l15+16, +32, +48}
#pragma unroll
    for (int k = 0; k < 9; ++k) { MV[tid * 9 + k] = sv[k]; MJ[tid * 9 + k] = sj[k]; }
    __syncthreads();
    if (tid < 64) {                            // i = i0 + tid  (wsrc = tid>>4, r = tid&15)
        float mv[9]; int mj[9];
#pragma unroll
        for (int k = 0; k < 9; ++k) { mv[k] = -FLT_MAX; mj[k] = 0x7fffffff; }
        const int wsrc = tid >> 4, r = tid & 15;
        for (int q2 = 0; q2 < 4; ++q2) {
            const int src = wsrc * 64 + q2 * 16 + r;
            for (int k = 0; k < 9; ++k)
                topk_insert(mv, mj, MV[src * 9 + k], MJ[src * 9 + k]);
        }
        const int base = ((b * 4096 + i0 + tid) * NSPLIT + js) * 9;
#pragma unroll
        for (int k = 0; k < 9; ++k) { pv[base + k] = mv[k]; pj[base + k] = mj[k]; }
    }
}

// ---- Kernel M: merge 8 split-lists -> final 9 indices per row ----
__global__ __launch_bounds__(256) void merge_kernel(const float* __restrict__ pv,
                                                    const int* __restrict__ pj,
                                                    int* __restrict__ nn) {
    int t = blockIdx.x * 256 + threadIdx.x;
    float sv[9]; int sj[9];
#pragma unroll
    for (int k = 0; k < 9; ++k) { sv[k] = -FLT_MAX; sj[k] = 0x7fffffff; }
    int base = t * (NSPLIT * 9);
    for (int s = 0; s < NSPLIT * 9; ++s) topk_insert(sv, sj, pv[base + s], pj[base + s]);
#pragma unroll
    for (int k = 0; k < 9; ++k) nn[t * 9 + k] = sj[k];
}

// ---- Kernel C: P/Q GEMM (fp32, unchanged) ----
__global__ __launch_bounds__(256, 2) void pq_kernel(const float* __restrict__ xn,
                                                    const float* __restrict__ wt,
                                                    const float* __restrict__ rnv,
                                                    float* __restrict__ q,
                                                    float* __restrict__ out) {
    __shared__ float Xs[128][64];
    __shared__ float Ws[128][64];
    const int b = blockIdx.z;
    const int n0 = blockIdx.x * 64;
    const int o0 = blockIdx.y * 64;
    const int tid = threadIdx.x;
    {
        const int c4 = tid >> 4, j4 = (tid & 15) * 4;
#pragma unroll
        for (int cc = 0; cc < 8; ++cc) {
            int c = cc * 16 + c4;
            *(float4*)&Xs[c][j4] = *(const float4*)&xn[((size_t)(b * 128 + c)) * 4096 + n0 + j4];
            *(float4*)&Ws[c][j4] = *(const float4*)&wt[c * 512 + o0 + j4];
        }
    }
    __syncthreads();
    const int tx = tid & 15, ty = tid >> 4;
    float acc[4][4];
#pragma unroll
    for (int i = 0; i < 4; ++i)
#pragma unroll
        for (int j = 0; j < 4; ++j) acc[i][j] = 0.f;
#pragma unroll 4
    for (int c = 0; c < 128; ++c) {
        const float4 av = *(const float4*)&Xs[c][ty * 4];
        const float4 bv = *(const float4*)&Ws[c][tx * 4];
        const float ar[4] = {av.x, av.y, av.z, av.w};
        const float br[4] = {bv.x, bv.y, bv.z, bv.w};
#pragma unroll
        for (int i = 0; i < 4; ++i)
#pragma unroll
            for (int j = 0; j < 4; ++j) acc[i][j] = fmaf(ar[i], br[j], acc[i][j]);
    }
    const float4 rv = *(const float4*)&rnv[b * 4096 + n0 + ty * 4];
    if (o0 < 256) {
#pragma unroll
        for (int j = 0; j < 4; ++j) {
            float4 v = make_float4(acc[0][j] * rv.x, acc[1][j] * rv.y,
                                   acc[2][j] * rv.z, acc[3][j] * rv.w);
            *(float4*)&out[((size_t)(b * 256 + o0 + tx * 4 + j)) * 4096 + n0 + ty * 4] = v;
        }
    } else {
        const float rr[4] = {rv.x, rv.y, rv.z, rv.w};
#pragma unroll
        for (int i = 0; i < 4; ++i) {
            float4 v = make_float4(acc[i][0] * rr[i], acc[i][1] * rr[i],
                                   acc[i][2] * rr[i], acc[i][3] * rr[i]);
            *(float4*)&q[((size_t)(b * 4096 + n0 + ty * 4 + i)) * 256 + (o0 - 256) + tx * 4] = v;
        }
    }
}

// ---- Kernel D: out = relu(P(out) + bias + max_k Q[nn]) in place (unchanged) ----
__global__ __launch_bounds__(256) void gather_kernel(const float* __restrict__ q,
                                                     const int* __restrict__ nn,
                                                     const float* __restrict__ bias,
                                                     float* __restrict__ out) {
    __shared__ int idx[32][9];
    const int b = blockIdx.y, n0 = blockIdx.x * 32;
    const int tid = threadIdx.x;
    for (int t = tid; t < 288; t += 256) {
        int pt = t / 9, k = t - pt * 9;
        idx[pt][k] = nn[(b * 4096 + n0 + pt) * 9 + k];
    }
    __syncthreads();
    const float bv = bias[tid];
    const size_t orow = ((size_t)(b * 256 + tid)) * 4096 + n0;
    float pvals[32];
#pragma unroll
    for (int u = 0; u < 8; ++u)
        *(float4*)&pvals[u * 4] = *(const float4*)&out[orow + u * 4];
    float val[32];
#pragma unroll
    for (int pt = 0; pt < 32; ++pt) {
        float m = -FLT_MAX;
#pragma unroll
        for (int k = 0; k < 9; ++k) {
            int j = idx[pt][k] & 4095;
            m = fmaxf(m, q[((size_t)(b * 4096 + j)) * 256 + tid]);
        }
        float vv = pvals[pt] + bv + m;
        val[pt] = vv > 0.f ? vv : 0.f;
    }
#pragma unroll
    for (int u = 0; u < 8; ++u) {
        float4 v = make_float4(val[u * 4], val[u * 4 + 1], val[u * 4 + 2], val[u * 4 + 3]);
        *(float4*)&out[orow + u * 4] = v;
    }
}

extern "C" void kernel_launch(void* const* d_in, const int* in_sizes, int n_in,
                              void* d_out, int out_size, void* d_ws, size_t ws_size,
                              hipStream_t stream) {
    const float* x    = (const float*)d_in[0];
    const float* w    = (const float*)d_in[1];
    const float* bias = (const float*)d_in[2];
    float* ws = (float*)d_ws;
    float* xn = ws + OFF_XN;
    float* sq = ws + OFF_SQ;
    float* rn = ws + OFF_RN;
    float* wt = ws + OFF_WT;
    float* q  = ws + OFF_Q;
    unsigned short* xh = (unsigned short*)(ws + OFF_Q);        // planes overlay Q
    unsigned short* xm = xh + (size_t)CB * CN * CC;
    unsigned short* xl = xm + (size_t)CB * CN * CC;
    float* pv = ws + OFF_PV;
    int*   pj = (int*)(ws + OFF_PJ);
    int*   nn = (int*)(ws + OFF_NN);
    float* out = (float*)d_out;

    prep_kernel  <<<dim3(64, 2),    256, 0, stream>>>(x, xn, sq, rn, xh, xm, xl);
    wprep_kernel <<<dim3(256),      256, 0, stream>>>(w, wt);
    knn_kernel   <<<dim3(8, 64, 2), 256, 0, stream>>>(xh, xm, xl, sq, pv, pj);
    merge_kernel <<<dim3(32),       256, 0, stream>>>(pv, pj, nn);
    pq_kernel    <<<dim3(64, 8, 2), 256, 0, stream>>>(xn, wt, rn, q, out);
    gather_kernel<<<dim3(128, 2),   256, 0, stream>>>(q, nn, bias, out);
}

// Round 13
// 264.021 us; speedup vs baseline: 1.5078x; 1.2988x over previous
//
#include <hip/hip_runtime.h>
#include <float.h>

// Problem constants: x (2,128,64,64) fp32, w (256,256) fp32, b (256,) fp32
// out (2,256,64,64) fp32. K=9 nearest neighbors on normalized features.
constexpr int CB = 2;      // batch
constexpr int CC = 128;    // channels
constexpr int CN = 4096;   // points (64*64)
constexpr int CO2 = 512;   // P(256) + Q(256) packed weight columns
constexpr int NSPLIT = 8;  // knn col-splits

// ---- workspace layout (float offsets) ----
// bf16x3 planes (6MB) OVERLAY the Q region (8MB): planes are consumed by
// knn_kernel BEFORE pq_kernel writes Q (same stream, serialized).
constexpr size_t OFF_XN = 0;                                  // [B][C][N] normalized x (fp32)
constexpr size_t OFF_SQ = OFF_XN + (size_t)CB * CC * CN;      // [B][N] sum(xn^2)
constexpr size_t OFF_RN = OFF_SQ + (size_t)CB * CN;           // [B][N] norm
constexpr size_t OFF_WT = OFF_RN + (size_t)CB * CN;           // [C][512] (W1-W2 | W2)^T
constexpr size_t OFF_Q  = OFF_WT + (size_t)CC * CO2;          // [B][N][256] Q (fp32)
constexpr size_t OFF_PV = OFF_Q  + (size_t)CB * CN * 256;     // [B][N][8][9] vals
constexpr size_t OFF_PJ = OFF_PV + (size_t)CB * CN * 72;      // [B][N][8][9] idx
constexpr size_t OFF_NN = OFF_PJ + (size_t)CB * CN * 72;      // [B][N][9] final idx

typedef __attribute__((ext_vector_type(8))) short bf16x8;
typedef __attribute__((ext_vector_type(4))) float f32x4;

__device__ __forceinline__ unsigned short f2bf(float f) {
    unsigned int u = __float_as_uint(f);
    unsigned int r = (u + 0x7FFFu + ((u >> 16) & 1u)) >> 16;   // round-nearest-even
    return (unsigned short)r;
}
__device__ __forceinline__ float bf2f(unsigned short h) {
    return __uint_as_float(((unsigned int)h) << 16);
}

// top-9 sorted-desc insert; comparator matches jax.lax.top_k tie-break.
// Result = top-9 under a total order -> independent of scan order.
__device__ __forceinline__ void topk_insert(float (&sv)[9], int (&sj)[9], float v, int jg) {
    if ((v > sv[8]) || (v == sv[8] && jg < sj[8])) {
        bool bb[9];
#pragma unroll
        for (int k = 0; k < 9; ++k) bb[k] = (v > sv[k]) || (v == sv[k] && jg < sj[k]);
#pragma unroll
        for (int k = 8; k >= 1; --k) {
            sv[k] = bb[k - 1] ? sv[k - 1] : (bb[k] ? v : sv[k]);
            sj[k] = bb[k - 1] ? sj[k - 1] : (bb[k] ? jg : sj[k]);
        }
        sv[0] = bb[0] ? v : sv[0];
        sj[0] = bb[0] ? jg : sj[0];
    }
}

// ---- Kernel A: normalize + emit bf16x3 planes in FRAGMENT-MAJOR layout ----
// plane[b][g=n>>4][q=c>>3][r=n&15][e=c&7] (shorts): a knn frag load becomes
// one contiguous 1KiB wave-burst (r12 binder: [n][c] rows made every frag load
// a 16-scattered-line gather -> TA line-pipe bound at ~248us).
__global__ __launch_bounds__(256) void prep_kernel(const float* __restrict__ x,
                                                   float* __restrict__ xn,
                                                   float* __restrict__ sqv,
                                                   float* __restrict__ rnv,
                                                   unsigned short* __restrict__ xh,
                                                   unsigned short* __restrict__ xm,
                                                   unsigned short* __restrict__ xl) {
    __shared__ float XT[128][65];              // +1 pad: column reads conflict-free
    __shared__ float red[4][64];
    __shared__ float invl[64];
    const int b = blockIdx.y, n0 = blockIdx.x * 64;
    const int tid = threadIdx.x;
    const int nl = tid & 63, c0 = tid >> 6;
#pragma unroll 4
    for (int cc = 0; cc < 32; ++cc) {
        int c = cc * 4 + c0;
        XT[c][nl] = x[((size_t)(b * 128 + c)) * 4096 + n0 + nl];
    }
    __syncthreads();
    {
        float acc = 0.f;
#pragma unroll 4
        for (int cc = 0; cc < 32; ++cc) { float v = XT[c0 * 32 + cc][nl]; acc += v * v; }
        red[c0][nl] = acc;
    }
    __syncthreads();
    if (tid < 64) {
        float ss = red[0][tid] + red[1][tid] + red[2][tid] + red[3][tid] + 1e-12f;
        float sr = sqrtf(ss);
        invl[tid] = 1.0f / sr;
        rnv[b * 4096 + n0 + tid] = sr;
    }
    __syncthreads();
    {
        float acc = 0.f;
        float iv = invl[nl];
#pragma unroll 4
        for (int cc = 0; cc < 32; ++cc) {
            int c = cc * 4 + c0;
            float v = XT[c][nl] * iv;
            xn[((size_t)(b * 128 + c)) * 4096 + n0 + nl] = v;
            XT[c][nl] = v;                     // keep normalized value for pass 3
            acc += v * v;
        }
        red[c0][nl] = acc;
    }
    __syncthreads();
    if (tid < 64) {
        sqv[b * 4096 + n0 + tid] = red[0][tid] + red[1][tid] + red[2][tid] + red[3][tid];
    }
    __syncthreads();
    // pass 3: bf16x3 split, fragment-major layout
    {
        const int n = tid & 63, cq = tid >> 6;     // thread: one n, c-block cq*32..+31
        unsigned short hs[32], ms[32], ls[32];
#pragma unroll
        for (int cc = 0; cc < 32; ++cc) {
            float v = XT[cq * 32 + cc][n];
            unsigned short h = f2bf(v);  float hf = bf2f(h);
            float r1 = v - hf;
            unsigned short m = f2bf(r1); float mf = bf2f(m);
            unsigned short l = f2bf(r1 - mf);
            hs[cc] = h; ms[cc] = m; ls[cc] = l;
        }
        const int g = (n0 >> 4) + (n >> 4), r = n & 15;
        // dst tile (b, g, q=cq*4+u), row r: contiguous 16B per (thread,u)
        const size_t gb = ((size_t)(b * 256 + g)) * 2048 + r * 8;
#pragma unroll
        for (int u = 0; u < 4; ++u) {
            const size_t off = gb + (size_t)(cq * 4 + u) * 128;
            *(float4*)&xh[off] = *(const float4*)&hs[u * 8];
            *(float4*)&xm[off] = *(const float4*)&ms[u * 8];
            *(float4*)&xl[off] = *(const float4*)&ls[u * 8];
        }
    }
}

// ---- Kernel W: WT[c][o] = (o<256) ? w[o][c]-w[o][128+c] : w[o-256][128+c] ----
__global__ __launch_bounds__(256) void wprep_kernel(const float* __restrict__ w,
                                                    float* __restrict__ wt) {
    int id = blockIdx.x * 256 + threadIdx.x;   // 65536 = 128*512
    int c = id >> 9, o = id & 511;
    float v;
    if (o < 256) v = w[o * 256 + c] - w[o * 256 + 128 + c];
    else         v = w[(o - 256) * 256 + 128 + c];
    wt[c * 512 + o] = v;
}

// ---- Kernel B v13: MFMA bf16x3 Gram, register scan, COALESCED frag loads ----
// = v12 with fragment-major plane layout: frag addr = group_base +
// (ch*4 + l4)*128 + l15*8 shorts -> lanes cover one contiguous 1KiB block
// per load (v12: 16 scattered 64B lines/load -> TA-bound ~248us).
// Same operand values -> selection bit-identical to r10-r12.
// mfma(J, I): D row = J-row ((lane>>4)*4+reg), D col = I-row (lane&15).
// Score s = 2*inner - sq_j (per-i shift preserves order+ties; merge shares i).
// Zero barriers / zero LDS in the main loop; per-wave tile stagger.
__global__ __launch_bounds__(256, 4) void knn_kernel(const unsigned short* __restrict__ xh,
                                                     const unsigned short* __restrict__ xm,
                                                     const unsigned short* __restrict__ xl,
                                                     const float* __restrict__ sqv,
                                                     float* __restrict__ pv,
                                                     int* __restrict__ pj) {
    __shared__ float lds[4608];                // 18,432 B: MV[256][9] + MJ[256][9]
    float* MV = lds;
    int*   MJ = (int*)(lds + 2304);

    const int b  = blockIdx.z;
    const int i0 = blockIdx.y * 64;
    const int js = blockIdx.x;                 // cols js*512 .. +511
    const int tid = threadIdx.x;
    const int lane = tid & 63, w = tid >> 6;
    const int l15 = lane & 15, l4 = lane >> 4;

    // I group base: g_i = (i0>>4) + w ; per-chunk offset koff shared with J
    const size_t ib0 = ((size_t)(b * 256 + (i0 >> 4) + w)) * 2048;
    float sv[9]; int sj[9];
#pragma unroll
    for (int k = 0; k < 9; ++k) { sv[k] = -FLT_MAX; sj[k] = 0x7fffffff; }

    for (int tt = 0; tt < 8; ++tt) {
        const int t = (tt + w * 2) & 7;        // stagger: waves desynchronized
        const int jt = js * 512 + t * 64;
        const size_t jb0 = ((size_t)(b * 256 + (jt >> 4))) * 2048;  // + Y*2048
        f32x4 a0 = {0.f, 0.f, 0.f, 0.f}, a1 = a0, a2 = a0, a3 = a0;

#pragma unroll
        for (int ch = 0; ch < 4; ++ch) {       // K chunks of 32; no barriers
            const int koff = (ch * 4 + l4) * 128 + l15 * 8;   // shorts, 1KiB/wave
            const bf16x8 ih = *(const bf16x8*)(xh + ib0 + koff);
            const bf16x8 im = *(const bf16x8*)(xm + ib0 + koff);
            const bf16x8 il = *(const bf16x8*)(xl + ib0 + koff);
#define DO_Y(ACC, Y)                                                          \
            {                                                                 \
                const bf16x8 jh = *(const bf16x8*)(xh + jb0 + (Y) * 2048 + koff); \
                const bf16x8 jm = *(const bf16x8*)(xm + jb0 + (Y) * 2048 + koff); \
                const bf16x8 jl = *(const bf16x8*)(xl + jb0 + (Y) * 2048 + koff); \
                ACC = __builtin_amdgcn_mfma_f32_16x16x32_bf16(jh, ih, ACC, 0, 0, 0); \
                ACC = __builtin_amdgcn_mfma_f32_16x16x32_bf16(jh, im, ACC, 0, 0, 0); \
                ACC = __builtin_amdgcn_mfma_f32_16x16x32_bf16(jm, ih, ACC, 0, 0, 0); \
                ACC = __builtin_amdgcn_mfma_f32_16x16x32_bf16(jm, im, ACC, 0, 0, 0); \
                ACC = __builtin_amdgcn_mfma_f32_16x16x32_bf16(jh, il, ACC, 0, 0, 0); \
                ACC = __builtin_amdgcn_mfma_f32_16x16x32_bf16(jl, ih, ACC, 0, 0, 0); \
            }
            DO_Y(a0, 0) DO_Y(a1, 1) DO_Y(a2, 2) DO_Y(a3, 3)
#undef DO_Y
        }
        // register-resident scan: lane's j = jt + Y*16 + l4*4 + reg
#define SCAN_Y(ACC, Y)                                                        \
        {                                                                     \
            const float4 sq4 = *(const float4*)&sqv[b * 4096 + jt + (Y) * 16 + l4 * 4]; \
            topk_insert(sv, sj, 2.0f * ACC[0] - sq4.x, jt + (Y) * 16 + l4 * 4 + 0); \
            topk_insert(sv, sj, 2.0f * ACC[1] - sq4.y, jt + (Y) * 16 + l4 * 4 + 1); \
            topk_insert(sv, sj, 2.0f * ACC[2] - sq4.z, jt + (Y) * 16 + l4 * 4 + 2); \
            topk_insert(sv, sj, 2.0f * ACC[3] - sq4.w, jt + (Y) * 16 + l4 * 4 + 3); \
        }
        SCAN_Y(a0, 0) SCAN_Y(a1, 1) SCAN_Y(a2, 2) SCAN_Y(a3, 3)
#undef SCAN_Y
    }
    // merge: i-row (w*16 + l15) has 4 lists, at lanes {l15, l15+16, +32, +48}
#pragma unroll
    for (int k = 0; k < 9; ++k) { MV[tid * 9 + k] = sv[k]; MJ[tid * 9 + k] = sj[k]; }
    __syncthreads();
    if (tid < 64) {                            // i = i0 + tid  (wsrc = tid>>4, r = tid&15)
        float mv[9]; int mj[9];
#pragma unroll
        for (int k = 0; k < 9; ++k) { mv[k] = -FLT_MAX; mj[k] = 0x7fffffff; }
        const int wsrc = tid >> 4, r = tid & 15;
        for (int q2 = 0; q2 < 4; ++q2) {
            const int src = wsrc * 64 + q2 * 16 + r;
            for (int k = 0; k < 9; ++k)
                topk_insert(mv, mj, MV[src * 9 + k], MJ[src * 9 + k]);
        }
        const int base = ((b * 4096 + i0 + tid) * NSPLIT + js) * 9;
#pragma unroll
        for (int k = 0; k < 9; ++k) { pv[base + k] = mv[k]; pj[base + k] = mj[k]; }
    }
}

// ---- Kernel M: merge 8 split-lists -> final 9 indices per row ----
__global__ __launch_bounds__(256) void merge_kernel(const float* __restrict__ pv,
                                                    const int* __restrict__ pj,
                                                    int* __restrict__ nn) {
    int t = blockIdx.x * 256 + threadIdx.x;
    float sv[9]; int sj[9];
#pragma unroll
    for (int k = 0; k < 9; ++k) { sv[k] = -FLT_MAX; sj[k] = 0x7fffffff; }
    int base = t * (NSPLIT * 9);
    for (int s = 0; s < NSPLIT * 9; ++s) topk_insert(sv, sj, pv[base + s], pj[base + s]);
#pragma unroll
    for (int k = 0; k < 9; ++k) nn[t * 9 + k] = sj[k];
}

// ---- Kernel C: P/Q GEMM (fp32, unchanged) ----
__global__ __launch_bounds__(256, 2) void pq_kernel(const float* __restrict__ xn,
                                                    const float* __restrict__ wt,
                                                    const float* __restrict__ rnv,
                                                    float* __restrict__ q,
                                                    float* __restrict__ out) {
    __shared__ float Xs[128][64];
    __shared__ float Ws[128][64];
    const int b = blockIdx.z;
    const int n0 = blockIdx.x * 64;
    const int o0 = blockIdx.y * 64;
    const int tid = threadIdx.x;
    {
        const int c4 = tid >> 4, j4 = (tid & 15) * 4;
#pragma unroll
        for (int cc = 0; cc < 8; ++cc) {
            int c = cc * 16 + c4;
            *(float4*)&Xs[c][j4] = *(const float4*)&xn[((size_t)(b * 128 + c)) * 4096 + n0 + j4];
            *(float4*)&Ws[c][j4] = *(const float4*)&wt[c * 512 + o0 + j4];
        }
    }
    __syncthreads();
    const int tx = tid & 15, ty = tid >> 4;
    float acc[4][4];
#pragma unroll
    for (int i = 0; i < 4; ++i)
#pragma unroll
        for (int j = 0; j < 4; ++j) acc[i][j] = 0.f;
#pragma unroll 4
    for (int c = 0; c < 128; ++c) {
        const float4 av = *(const float4*)&Xs[c][ty * 4];
        const float4 bv = *(const float4*)&Ws[c][tx * 4];
        const float ar[4] = {av.x, av.y, av.z, av.w};
        const float br[4] = {bv.x, bv.y, bv.z, bv.w};
#pragma unroll
        for (int i = 0; i < 4; ++i)
#pragma unroll
            for (int j = 0; j < 4; ++j) acc[i][j] = fmaf(ar[i], br[j], acc[i][j]);
    }
    const float4 rv = *(const float4*)&rnv[b * 4096 + n0 + ty * 4];
    if (o0 < 256) {
#pragma unroll
        for (int j = 0; j < 4; ++j) {
            float4 v = make_float4(acc[0][j] * rv.x, acc[1][j] * rv.y,
                                   acc[2][j] * rv.z, acc[3][j] * rv.w);
            *(float4*)&out[((size_t)(b * 256 + o0 + tx * 4 + j)) * 4096 + n0 + ty * 4] = v;
        }
    } else {
        const float rr[4] = {rv.x, rv.y, rv.z, rv.w};
#pragma unroll
        for (int i = 0; i < 4; ++i) {
            float4 v = make_float4(acc[i][0] * rr[i], acc[i][1] * rr[i],
                                   acc[i][2] * rr[i], acc[i][3] * rr[i]);
            *(float4*)&q[((size_t)(b * 4096 + n0 + ty * 4 + i)) * 256 + (o0 - 256) + tx * 4] = v;
        }
    }
}

// ---- Kernel D: out = relu(P(out) + bias + max_k Q[nn]) in place (unchanged) ----
__global__ __launch_bounds__(256) void gather_kernel(const float* __restrict__ q,
                                                     const int* __restrict__ nn,
                                                     const float* __restrict__ bias,
                                                     float* __restrict__ out) {
    __shared__ int idx[32][9];
    const int b = blockIdx.y, n0 = blockIdx.x * 32;
    const int tid = threadIdx.x;
    for (int t = tid; t < 288; t += 256) {
        int pt = t / 9, k = t - pt * 9;
        idx[pt][k] = nn[(b * 4096 + n0 + pt) * 9 + k];
    }
    __syncthreads();
    const float bv = bias[tid];
    const size_t orow = ((size_t)(b * 256 + tid)) * 4096 + n0;
    float pvals[32];
#pragma unroll
    for (int u = 0; u < 8; ++u)
        *(float4*)&pvals[u * 4] = *(const float4*)&out[orow + u * 4];
    float val[32];
#pragma unroll
    for (int pt = 0; pt < 32; ++pt) {
        float m = -FLT_MAX;
#pragma unroll
        for (int k = 0; k < 9; ++k) {
            int j = idx[pt][k] & 4095;
            m = fmaxf(m, q[((size_t)(b * 4096 + j)) * 256 + tid]);
        }
        float vv = pvals[pt] + bv + m;
        val[pt] = vv > 0.f ? vv : 0.f;
    }
#pragma unroll
    for (int u = 0; u < 8; ++u) {
        float4 v = make_float4(val[u * 4], val[u * 4 + 1], val[u * 4 + 2], val[u * 4 + 3]);
        *(float4*)&out[orow + u * 4] = v;
    }
}

extern "C" void kernel_launch(void* const* d_in, const int* in_sizes, int n_in,
                              void* d_out, int out_size, void* d_ws, size_t ws_size,
                              hipStream_t stream) {
    const float* x    = (const float*)d_in[0];
    const float* w    = (const float*)d_in[1];
    const float* bias = (const float*)d_in[2];
    float* ws = (float*)d_ws;
    float* xn = ws + OFF_XN;
    float* sq = ws + OFF_SQ;
    float* rn = ws + OFF_RN;
    float* wt = ws + OFF_WT;
    float* q  = ws + OFF_Q;
    unsigned short* xh = (unsigned short*)(ws + OFF_Q);        // planes overlay Q
    unsigned short* xm = xh + (size_t)CB * CN * CC;
    unsigned short* xl = xm + (size_t)CB * CN * CC;
    float* pv = ws + OFF_PV;
    int*   pj = (int*)(ws + OFF_PJ);
    int*   nn = (int*)(ws + OFF_NN);
    float* out = (float*)d_out;

    prep_kernel  <<<dim3(64, 2),    256, 0, stream>>>(x, xn, sq, rn, xh, xm, xl);
    wprep_kernel <<<dim3(256),      256, 0, stream>>>(w, wt);
    knn_kernel   <<<dim3(8, 64, 2), 256, 0, stream>>>(xh, xm, xl, sq, pv, pj);
    merge_kernel <<<dim3(32),       256, 0, stream>>>(pv, pj, nn);
    pq_kernel    <<<dim3(64, 8, 2), 256, 0, stream>>>(xn, wt, rn, q, out);
    gather_kernel<<<dim3(128, 2),   256, 0, stream>>>(q, nn, bias, out);
}

// Round 14
// 208.282 us; speedup vs baseline: 1.9113x; 1.2676x over previous
//
#include <hip/hip_runtime.h>
#include <float.h>

// Problem constants: x (2,128,64,64) fp32, w (256,256) fp32, b (256,) fp32
// out (2,256,64,64) fp32. K=9 nearest neighbors on normalized features.
constexpr int CB = 2;      // batch
constexpr int CC = 128;    // channels
constexpr int CN = 4096;   // points (64*64)
constexpr int CO2 = 512;   // P(256) + Q(256) packed weight columns
constexpr int NSPLIT = 8;  // knn col-splits

typedef unsigned long long u64;

// ---- workspace layout (float offsets) ----
// bf16x3 planes (6MB) OVERLAY the Q region (8MB): planes are consumed by
// knn_kernel BEFORE pq_kernel writes Q (same stream, serialized).
constexpr size_t OFF_XN = 0;                                  // [B][C][N] normalized x (fp32)
constexpr size_t OFF_SQ = OFF_XN + (size_t)CB * CC * CN;      // [B][N] sum(xn^2)
constexpr size_t OFF_RN = OFF_SQ + (size_t)CB * CN;           // [B][N] norm
constexpr size_t OFF_WT = OFF_RN + (size_t)CB * CN;           // [C][512] (W1-W2 | W2)^T
constexpr size_t OFF_Q  = OFF_WT + (size_t)CC * CO2;          // [B][N][256] Q (fp32)
constexpr size_t OFF_PK = OFF_Q  + (size_t)CB * CN * 256;     // [B][N][8][9] u64 keys
constexpr size_t OFF_NN = OFF_PK + (size_t)CB * CN * 144;     // [B][N][9] final idx

typedef __attribute__((ext_vector_type(8))) short bf16x8;
typedef __attribute__((ext_vector_type(4))) float f32x4;

__device__ __forceinline__ unsigned short f2bf(float f) {
    unsigned int u = __float_as_uint(f);
    unsigned int r = (u + 0x7FFFu + ((u >> 16) & 1u)) >> 16;   // round-nearest-even
    return (unsigned short)r;
}
__device__ __forceinline__ float bf2f(unsigned short h) {
    return __uint_as_float(((unsigned int)h) << 16);
}

// ---- u64-key top-9 set machinery ----
// Key = mono(score) << 12 | (4095 - j): numerically-larger key == better under
// the EXACT jax.lax.top_k order (score desc, index asc on ties). mono() is the
// standard monotone float->uint map. Keys are globally unique (each j scanned
// once per row) -> the min of a 9-set is unique -> replace-min by equality.
// Only the SET of 9 neighbors matters (output is max over k), so an unsorted
// set is equivalent to the reference's sorted list.
__device__ __forceinline__ unsigned int mono32(float v) {
    unsigned int u = __float_as_uint(v);
    unsigned int m = (unsigned int)((int)u >> 31);
    return u ^ (m | 0x80000000u);
}
__device__ __forceinline__ u64 make_key(float v, int jg) {
    return ((u64)mono32(v) << 12) | (unsigned int)(4095 - jg);
}
// sk: 9 unique keys (unsorted), kmin == min(sk). ~1 inst reject, ~51 accept.
__device__ __forceinline__ void key_insert(u64 (&sk)[9], u64& kmin, u64 key) {
    if (key > kmin) {
#pragma unroll
        for (int k = 0; k < 9; ++k) sk[k] = (sk[k] == kmin) ? key : sk[k];
        u64 m = sk[0];
#pragma unroll
        for (int k = 1; k < 9; ++k) m = (sk[k] < m) ? sk[k] : m;
        kmin = m;
    }
}
// init: distinct sentinels 0..8, all below any real key (real keys have
// mono(finite)<<12 >= 0x00800000<<12); >=512 real candidates flush them.
__device__ __forceinline__ void key_init(u64 (&sk)[9], u64& kmin) {
#pragma unroll
    for (int k = 0; k < 9; ++k) sk[k] = (u64)k;
    kmin = 0;
}

// ---- Kernel A: normalize + emit bf16x3 planes in FRAGMENT-MAJOR layout ----
// plane[b][g=n>>4][q=c>>3][r=n&15][e=c&7] (shorts): a knn frag load becomes
// one contiguous 1KiB wave-burst (r12->r13: -33%, TA line-pipe was binder).
__global__ __launch_bounds__(256) void prep_kernel(const float* __restrict__ x,
                                                   float* __restrict__ xn,
                                                   float* __restrict__ sqv,
                                                   float* __restrict__ rnv,
                                                   unsigned short* __restrict__ xh,
                                                   unsigned short* __restrict__ xm,
                                                   unsigned short* __restrict__ xl) {
    __shared__ float XT[128][65];              // +1 pad: column reads conflict-free
    __shared__ float red[4][64];
    __shared__ float invl[64];
    const int b = blockIdx.y, n0 = blockIdx.x * 64;
    const int tid = threadIdx.x;
    const int nl = tid & 63, c0 = tid >> 6;
#pragma unroll 4
    for (int cc = 0; cc < 32; ++cc) {
        int c = cc * 4 + c0;
        XT[c][nl] = x[((size_t)(b * 128 + c)) * 4096 + n0 + nl];
    }
    __syncthreads();
    {
        float acc = 0.f;
#pragma unroll 4
        for (int cc = 0; cc < 32; ++cc) { float v = XT[c0 * 32 + cc][nl]; acc += v * v; }
        red[c0][nl] = acc;
    }
    __syncthreads();
    if (tid < 64) {
        float ss = red[0][tid] + red[1][tid] + red[2][tid] + red[3][tid] + 1e-12f;
        float sr = sqrtf(ss);
        invl[tid] = 1.0f / sr;
        rnv[b * 4096 + n0 + tid] = sr;
    }
    __syncthreads();
    {
        float acc = 0.f;
        float iv = invl[nl];
#pragma unroll 4
        for (int cc = 0; cc < 32; ++cc) {
            int c = cc * 4 + c0;
            float v = XT[c][nl] * iv;
            xn[((size_t)(b * 128 + c)) * 4096 + n0 + nl] = v;
            XT[c][nl] = v;                     // keep normalized value for pass 3
            acc += v * v;
        }
        red[c0][nl] = acc;
    }
    __syncthreads();
    if (tid < 64) {
        sqv[b * 4096 + n0 + tid] = red[0][tid] + red[1][tid] + red[2][tid] + red[3][tid];
    }
    __syncthreads();
    // pass 3: bf16x3 split, fragment-major layout
    {
        const int n = tid & 63, cq = tid >> 6;     // thread: one n, c-block cq*32..+31
        unsigned short hs[32], ms[32], ls[32];
#pragma unroll
        for (int cc = 0; cc < 32; ++cc) {
            float v = XT[cq * 32 + cc][n];
            unsigned short h = f2bf(v);  float hf = bf2f(h);
            float r1 = v - hf;
            unsigned short m = f2bf(r1); float mf = bf2f(m);
            unsigned short l = f2bf(r1 - mf);
            hs[cc] = h; ms[cc] = m; ls[cc] = l;
        }
        const int g = (n0 >> 4) + (n >> 4), r = n & 15;
        const size_t gb = ((size_t)(b * 256 + g)) * 2048 + r * 8;
#pragma unroll
        for (int u = 0; u < 4; ++u) {
            const size_t off = gb + (size_t)(cq * 4 + u) * 128;
            *(float4*)&xh[off] = *(const float4*)&hs[u * 8];
            *(float4*)&xm[off] = *(const float4*)&ms[u * 8];
            *(float4*)&xl[off] = *(const float4*)&ls[u * 8];
        }
    }
}

// ---- Kernel W: WT[c][o] = (o<256) ? w[o][c]-w[o][128+c] : w[o-256][128+c] ----
__global__ __launch_bounds__(256) void wprep_kernel(const float* __restrict__ w,
                                                    float* __restrict__ wt) {
    int id = blockIdx.x * 256 + threadIdx.x;   // 65536 = 128*512
    int c = id >> 9, o = id & 511;
    float v;
    if (o < 256) v = w[o * 256 + c] - w[o * 256 + 128 + c];
    else         v = w[(o - 256) * 256 + 128 + c];
    wt[c * 512 + o] = v;
}

// ---- Kernel B v14: MFMA bf16x3 Gram, u64-key register scan ----
// = v13 with the sorted top-9 insert (~100 insts/body, wave-diverged ~13K
// insts/wave = the 70us VALU binder per r13 counters) replaced by the u64-key
// set insert (~51 insts/body, 1-inst reject). Same total order -> same set.
// Loads/MFMA/stagger identical to v13 (selection-equivalent).
__global__ __launch_bounds__(256, 4) void knn_kernel(const unsigned short* __restrict__ xh,
                                                     const unsigned short* __restrict__ xm,
                                                     const unsigned short* __restrict__ xl,
                                                     const float* __restrict__ sqv,
                                                     u64* __restrict__ pk) {
    __shared__ u64 MK[2304];                   // 18,432 B: [256][9] keys

    const int b  = blockIdx.z;
    const int i0 = blockIdx.y * 64;
    const int js = blockIdx.x;                 // cols js*512 .. +511
    const int tid = threadIdx.x;
    const int lane = tid & 63, w = tid >> 6;
    const int l15 = lane & 15, l4 = lane >> 4;

    // I group base: g_i = (i0>>4) + w
    const size_t ib0 = ((size_t)(b * 256 + (i0 >> 4) + w)) * 2048;
    u64 sk[9]; u64 kmin;
    key_init(sk, kmin);

    for (int tt = 0; tt < 8; ++tt) {
        const int t = (tt + w * 2) & 7;        // stagger: waves desynchronized
        const int jt = js * 512 + t * 64;
        const size_t jb0 = ((size_t)(b * 256 + (jt >> 4))) * 2048;  // + Y*2048
        f32x4 a0 = {0.f, 0.f, 0.f, 0.f}, a1 = a0, a2 = a0, a3 = a0;

#pragma unroll
        for (int ch = 0; ch < 4; ++ch) {       // K chunks of 32; no barriers
            const int koff = (ch * 4 + l4) * 128 + l15 * 8;   // shorts, 1KiB/wave
            const bf16x8 ih = *(const bf16x8*)(xh + ib0 + koff);
            const bf16x8 im = *(const bf16x8*)(xm + ib0 + koff);
            const bf16x8 il = *(const bf16x8*)(xl + ib0 + koff);
#define DO_Y(ACC, Y)                                                          \
            {                                                                 \
                const bf16x8 jh = *(const bf16x8*)(xh + jb0 + (Y) * 2048 + koff); \
                const bf16x8 jm = *(const bf16x8*)(xm + jb0 + (Y) * 2048 + koff); \
                const bf16x8 jl = *(const bf16x8*)(xl + jb0 + (Y) * 2048 + koff); \
                ACC = __builtin_amdgcn_mfma_f32_16x16x32_bf16(jh, ih, ACC, 0, 0, 0); \
                ACC = __builtin_amdgcn_mfma_f32_16x16x32_bf16(jh, im, ACC, 0, 0, 0); \
                ACC = __builtin_amdgcn_mfma_f32_16x16x32_bf16(jm, ih, ACC, 0, 0, 0); \
                ACC = __builtin_amdgcn_mfma_f32_16x16x32_bf16(jm, im, ACC, 0, 0, 0); \
                ACC = __builtin_amdgcn_mfma_f32_16x16x32_bf16(jh, il, ACC, 0, 0, 0); \
                ACC = __builtin_amdgcn_mfma_f32_16x16x32_bf16(jl, ih, ACC, 0, 0, 0); \
            }
            DO_Y(a0, 0) DO_Y(a1, 1) DO_Y(a2, 2) DO_Y(a3, 3)
#undef DO_Y
        }
        // register-resident scan: lane's j = jt + Y*16 + l4*4 + reg
#define SCAN_Y(ACC, Y)                                                        \
        {                                                                     \
            const int jb4 = jt + (Y) * 16 + l4 * 4;                           \
            const float4 sq4 = *(const float4*)&sqv[b * 4096 + jb4];          \
            key_insert(sk, kmin, make_key(fmaf(2.0f, ACC[0], -sq4.x), jb4 + 0)); \
            key_insert(sk, kmin, make_key(fmaf(2.0f, ACC[1], -sq4.y), jb4 + 1)); \
            key_insert(sk, kmin, make_key(fmaf(2.0f, ACC[2], -sq4.z), jb4 + 2)); \
            key_insert(sk, kmin, make_key(fmaf(2.0f, ACC[3], -sq4.w), jb4 + 3)); \
        }
        SCAN_Y(a0, 0) SCAN_Y(a1, 1) SCAN_Y(a2, 2) SCAN_Y(a3, 3)
#undef SCAN_Y
    }
    // merge: i-row (w*16 + l15) has 4 disjoint-j lists at lanes {l15 + 16*l4}
#pragma unroll
    for (int k = 0; k < 9; ++k) MK[tid * 9 + k] = sk[k];
    __syncthreads();
    if (tid < 64) {                            // i = i0 + tid
        u64 mk[9]; u64 mn;
        key_init(mk, mn);
        const int wsrc = tid >> 4, r = tid & 15;
        for (int q2 = 0; q2 < 4; ++q2) {
            const int src = wsrc * 64 + q2 * 16 + r;
            for (int k = 0; k < 9; ++k) key_insert(mk, mn, MK[src * 9 + k]);
        }
        const size_t base = ((size_t)(b * 4096 + i0 + tid) * NSPLIT + js) * 9;
#pragma unroll
        for (int k = 0; k < 9; ++k) pk[base + k] = mk[k];
    }
}

// ---- Kernel M: merge 8 split-lists (72 keys) -> final 9 indices per row ----
__global__ __launch_bounds__(256) void merge_kernel(const u64* __restrict__ pk,
                                                    int* __restrict__ nn) {
    int t = blockIdx.x * 256 + threadIdx.x;
    u64 mk[9]; u64 mn;
    key_init(mk, mn);
    const size_t base = (size_t)t * (NSPLIT * 9);
    for (int s = 0; s < NSPLIT * 9; ++s) key_insert(mk, mn, pk[base + s]);
#pragma unroll
    for (int k = 0; k < 9; ++k) nn[t * 9 + k] = 4095 - (int)(mk[k] & 4095);
}

// ---- Kernel C: P/Q GEMM (fp32, unchanged) ----
__global__ __launch_bounds__(256, 2) void pq_kernel(const float* __restrict__ xn,
                                                    const float* __restrict__ wt,
                                                    const float* __restrict__ rnv,
                                                    float* __restrict__ q,
                                                    float* __restrict__ out) {
    __shared__ float Xs[128][64];
    __shared__ float Ws[128][64];
    const int b = blockIdx.z;
    const int n0 = blockIdx.x * 64;
    const int o0 = blockIdx.y * 64;
    const int tid = threadIdx.x;
    {
        const int c4 = tid >> 4, j4 = (tid & 15) * 4;
#pragma unroll
        for (int cc = 0; cc < 8; ++cc) {
            int c = cc * 16 + c4;
            *(float4*)&Xs[c][j4] = *(const float4*)&xn[((size_t)(b * 128 + c)) * 4096 + n0 + j4];
            *(float4*)&Ws[c][j4] = *(const float4*)&wt[c * 512 + o0 + j4];
        }
    }
    __syncthreads();
    const int tx = tid & 15, ty = tid >> 4;
    float acc[4][4];
#pragma unroll
    for (int i = 0; i < 4; ++i)
#pragma unroll
        for (int j = 0; j < 4; ++j) acc[i][j] = 0.f;
#pragma unroll 4
    for (int c = 0; c < 128; ++c) {
        const float4 av = *(const float4*)&Xs[c][ty * 4];
        const float4 bv = *(const float4*)&Ws[c][tx * 4];
        const float ar[4] = {av.x, av.y, av.z, av.w};
        const float br[4] = {bv.x, bv.y, bv.z, bv.w};
#pragma unroll
        for (int i = 0; i < 4; ++i)
#pragma unroll
            for (int j = 0; j < 4; ++j) acc[i][j] = fmaf(ar[i], br[j], acc[i][j]);
    }
    const float4 rv = *(const float4*)&rnv[b * 4096 + n0 + ty * 4];
    if (o0 < 256) {
#pragma unroll
        for (int j = 0; j < 4; ++j) {
            float4 v = make_float4(acc[0][j] * rv.x, acc[1][j] * rv.y,
                                   acc[2][j] * rv.z, acc[3][j] * rv.w);
            *(float4*)&out[((size_t)(b * 256 + o0 + tx * 4 + j)) * 4096 + n0 + ty * 4] = v;
        }
    } else {
        const float rr[4] = {rv.x, rv.y, rv.z, rv.w};
#pragma unroll
        for (int i = 0; i < 4; ++i) {
            float4 v = make_float4(acc[i][0] * rr[i], acc[i][1] * rr[i],
                                   acc[i][2] * rr[i], acc[i][3] * rr[i]);
            *(float4*)&q[((size_t)(b * 4096 + n0 + ty * 4 + i)) * 256 + (o0 - 256) + tx * 4] = v;
        }
    }
}

// ---- Kernel D: out = relu(P(out) + bias + max_k Q[nn]) in place (unchanged) ----
__global__ __launch_bounds__(256) void gather_kernel(const float* __restrict__ q,
                                                     const int* __restrict__ nn,
                                                     const float* __restrict__ bias,
                                                     float* __restrict__ out) {
    __shared__ int idx[32][9];
    const int b = blockIdx.y, n0 = blockIdx.x * 32;
    const int tid = threadIdx.x;
    for (int t = tid; t < 288; t += 256) {
        int pt = t / 9, k = t - pt * 9;
        idx[pt][k] = nn[(b * 4096 + n0 + pt) * 9 + k];
    }
    __syncthreads();
    const float bv = bias[tid];
    const size_t orow = ((size_t)(b * 256 + tid)) * 4096 + n0;
    float pvals[32];
#pragma unroll
    for (int u = 0; u < 8; ++u)
        *(float4*)&pvals[u * 4] = *(const float4*)&out[orow + u * 4];
    float val[32];
#pragma unroll
    for (int pt = 0; pt < 32; ++pt) {
        float m = -FLT_MAX;
#pragma unroll
        for (int k = 0; k < 9; ++k) {
            int j = idx[pt][k] & 4095;
            m = fmaxf(m, q[((size_t)(b * 4096 + j)) * 256 + tid]);
        }
        float vv = pvals[pt] + bv + m;
        val[pt] = vv > 0.f ? vv : 0.f;
    }
#pragma unroll
    for (int u = 0; u < 8; ++u) {
        float4 v = make_float4(val[u * 4], val[u * 4 + 1], val[u * 4 + 2], val[u * 4 + 3]);
        *(float4*)&out[orow + u * 4] = v;
    }
}

extern "C" void kernel_launch(void* const* d_in, const int* in_sizes, int n_in,
                              void* d_out, int out_size, void* d_ws, size_t ws_size,
                              hipStream_t stream) {
    const float* x    = (const float*)d_in[0];
    const float* w    = (const float*)d_in[1];
    const float* bias = (const float*)d_in[2];
    float* ws = (float*)d_ws;
    float* xn = ws + OFF_XN;
    float* sq = ws + OFF_SQ;
    float* rn = ws + OFF_RN;
    float* wt = ws + OFF_WT;
    float* q  = ws + OFF_Q;
    unsigned short* xh = (unsigned short*)(ws + OFF_Q);        // planes overlay Q
    unsigned short* xm = xh + (size_t)CB * CN * CC;
    unsigned short* xl = xm + (size_t)CB * CN * CC;
    u64*   pk = (u64*)(ws + OFF_PK);
    int*   nn = (int*)(ws + OFF_NN);
    float* out = (float*)d_out;

    prep_kernel  <<<dim3(64, 2),    256, 0, stream>>>(x, xn, sq, rn, xh, xm, xl);
    wprep_kernel <<<dim3(256),      256, 0, stream>>>(w, wt);
    knn_kernel   <<<dim3(8, 64, 2), 256, 0, stream>>>(xh, xm, xl, sq, pk);
    merge_kernel <<<dim3(32),       256, 0, stream>>>(pk, nn);
    pq_kernel    <<<dim3(64, 8, 2), 256, 0, stream>>>(xn, wt, rn, q, out);
    gather_kernel<<<dim3(128, 2),   256, 0, stream>>>(q, nn, bias, out);
}

// Round 15
// 181.504 us; speedup vs baseline: 2.1933x; 1.1475x over previous
//
#include <hip/hip_runtime.h>
#include <float.h>

// Problem constants: x (2,128,64,64) fp32, w (256,256) fp32, b (256,) fp32
// out (2,256,64,64) fp32. K=9 nearest neighbors on normalized features.
constexpr int CB = 2;       // batch
constexpr int CC = 128;     // channels
constexpr int CN = 4096;    // points (64*64)
constexpr int NSPLIT = 16;  // knn col-splits (grid.x) -> 8 blocks/CU latent

typedef unsigned long long u64;
typedef unsigned int u32;

// ---- workspace layout (float offsets), total ~14.6 MB ----
// Lifetimes: planes (prep->knn), PK (knn->merge), Q (pq->gather).
// RegionA hosts planes (6MB) then Q (8MB): planes dead before pq writes Q.
// Reference features use RAW x (not normalized!) -> pq reads d_in[0]; no xn/rn.
constexpr size_t OFF_SQ = 0;                                  // [B][N] sum(xn^2)
constexpr size_t OFF_WT = OFF_SQ + (size_t)CB * CN;           // [C][512] (W1-W2 | W2)^T
constexpr size_t OFF_A  = OFF_WT + (size_t)CC * 512;          // RegionA: 2M floats
constexpr size_t OFF_PK = OFF_A + (size_t)CB * CN * 256;      // [B][N][16][12] u32
constexpr size_t OFF_NN = OFF_PK + (size_t)CB * CN * NSPLIT * 12 / 1; // (u32 units == float units)

typedef __attribute__((ext_vector_type(8))) short bf16x8;
typedef __attribute__((ext_vector_type(4))) float f32x4;

__device__ __forceinline__ unsigned short f2bf(float f) {
    u32 u = __float_as_uint(f);
    u32 r = (u + 0x7FFFu + ((u >> 16) & 1u)) >> 16;   // round-nearest-even
    return (unsigned short)r;
}
__device__ __forceinline__ float bf2f(unsigned short h) {
    return __uint_as_float(((u32)h) << 16);
}

// ---- u64-key top-9 machinery ----
// Key = mono(score)<<12 | (4095-j): larger key == better under the EXACT
// jax.lax.top_k order (score desc, index asc). Keys unique (j unique).
__device__ __forceinline__ u32 mono32(float v) {
    u32 u = __float_as_uint(v);
    u32 m = (u32)((int)u >> 31);
    return u ^ (m | 0x80000000u);
}
__device__ __forceinline__ u64 make_key(float v, int jg) {
    return ((u64)mono32(v) << 12) | (u32)(4095 - jg);
}
// sk sorted DESCENDING (sk[8] = min). Insertion-sort bubble pass: 9x
// {cmp_u64 + 4 cndmask} ~= 45 insts, UNCONDITIONAL (wave-any accept ~= 1, so a
// reject branch never skips at wave level -- r14's 90-inst replace-min body
// was the 64us VALU binder). Evicted min falls out in t.
__device__ __forceinline__ void key_insert(u64 (&sk)[9], u64 key) {
    u64 t = key;
#pragma unroll
    for (int k = 0; k < 9; ++k) {
        const bool gt = t > sk[k];
        const u64 hi = gt ? t : sk[k];
        t = gt ? sk[k] : t;
        sk[k] = hi;
    }
}
__device__ __forceinline__ void key_init(u64 (&sk)[9]) {
#pragma unroll
    for (int k = 0; k < 9; ++k) sk[k] = (u64)(8 - k);   // descending sentinels
}

// ---- Kernel A: normalize (registers/LDS only) + sq + bf16x3 planes ----
// Planes in FRAGMENT-MAJOR layout plane[b][g=n>>4][q=c>>3][r=n&15][e=c&7]:
// knn frag load = one contiguous 1KiB wave-burst (r13: -33% from this).
__global__ __launch_bounds__(256) void prep_kernel(const float* __restrict__ x,
                                                   float* __restrict__ sqv,
                                                   unsigned short* __restrict__ xh,
                                                   unsigned short* __restrict__ xm,
                                                   unsigned short* __restrict__ xl) {
    __shared__ float XT[128][65];
    __shared__ float red[4][64];
    __shared__ float invl[64];
    const int b = blockIdx.y, n0 = blockIdx.x * 64;
    const int tid = threadIdx.x;
    const int nl = tid & 63, c0 = tid >> 6;
#pragma unroll 4
    for (int cc = 0; cc < 32; ++cc) {
        int c = cc * 4 + c0;
        XT[c][nl] = x[((size_t)(b * 128 + c)) * 4096 + n0 + nl];
    }
    __syncthreads();
    {
        float acc = 0.f;
#pragma unroll 4
        for (int cc = 0; cc < 32; ++cc) { float v = XT[c0 * 32 + cc][nl]; acc += v * v; }
        red[c0][nl] = acc;
    }
    __syncthreads();
    if (tid < 64) {
        float ss = red[0][tid] + red[1][tid] + red[2][tid] + red[3][tid] + 1e-12f;
        invl[tid] = 1.0f / sqrtf(ss);
    }
    __syncthreads();
    {
        float acc = 0.f;
        float iv = invl[nl];
#pragma unroll 4
        for (int cc = 0; cc < 32; ++cc) {
            int c = cc * 4 + c0;
            float v = XT[c][nl] * iv;
            XT[c][nl] = v;
            acc += v * v;
        }
        red[c0][nl] = acc;
    }
    __syncthreads();
    if (tid < 64) {
        sqv[b * 4096 + n0 + tid] = red[0][tid] + red[1][tid] + red[2][tid] + red[3][tid];
    }
    __syncthreads();
    // bf16x3 split, fragment-major
    {
        const int n = tid & 63, cq = tid >> 6;
        unsigned short hs[32], ms[32], ls[32];
#pragma unroll
        for (int cc = 0; cc < 32; ++cc) {
            float v = XT[cq * 32 + cc][n];
            unsigned short h = f2bf(v);  float hf = bf2f(h);
            float r1 = v - hf;
            unsigned short m = f2bf(r1); float mf = bf2f(m);
            unsigned short l = f2bf(r1 - mf);
            hs[cc] = h; ms[cc] = m; ls[cc] = l;
        }
        const int g = (n0 >> 4) + (n >> 4), r = n & 15;
        const size_t gb = ((size_t)(b * 256 + g)) * 2048 + r * 8;
#pragma unroll
        for (int u = 0; u < 4; ++u) {
            const size_t off = gb + (size_t)(cq * 4 + u) * 128;
            *(float4*)&xh[off] = *(const float4*)&hs[u * 8];
            *(float4*)&xm[off] = *(const float4*)&ms[u * 8];
            *(float4*)&xl[off] = *(const float4*)&ls[u * 8];
        }
    }
}

// ---- Kernel W: WT[c][o] = (o<256) ? w[o][c]-w[o][128+c] : w[o-256][128+c] ----
__global__ __launch_bounds__(256) void wprep_kernel(const float* __restrict__ w,
                                                    float* __restrict__ wt) {
    int id = blockIdx.x * 256 + threadIdx.x;   // 65536 = 128*512
    int c = id >> 9, o = id & 511;
    float v;
    if (o < 256) v = w[o * 256 + c] - w[o * 256 + 128 + c];
    else         v = w[(o - 256) * 256 + 128 + c];
    wt[c * 512 + o] = v;
}

// ---- Kernel B v15: MFMA bf16x3 Gram, sorted-chain register scan ----
// NSPLIT=16: 64 candidates/lane (halves per-wave latency exposure), grid 2048
// -> 8 blocks/CU latent (VGPR ~64, LDS 18432B: 8x fits 160KB). Split output
// compressed to 12 u32 (9 mono-scores + 9 packed 8-bit local-j) to fit ws.
// mfma(J, I): D row = J-row ((lane>>4)*4+reg), D col = I-row (lane&15).
// Score s = 2*inner - sq_j (per-i shift preserves order+ties; merge shares i).
// Zero barriers / zero LDS in main loop; per-wave tile stagger.
__global__ __launch_bounds__(256, 4) void knn_kernel(const unsigned short* __restrict__ xh,
                                                     const unsigned short* __restrict__ xm,
                                                     const unsigned short* __restrict__ xl,
                                                     const float* __restrict__ sqv,
                                                     u32* __restrict__ pk) {
    __shared__ u64 MK[2304];                   // 18,432 B: [256][9] keys

    const int b  = blockIdx.z;
    const int i0 = blockIdx.y * 64;
    const int js = blockIdx.x;                 // 0..15, cols js*256 .. +255
    const int tid = threadIdx.x;
    const int lane = tid & 63, w = tid >> 6;
    const int l15 = lane & 15, l4 = lane >> 4;

    const size_t ib0 = ((size_t)(b * 256 + (i0 >> 4) + w)) * 2048;
    u64 sk[9];
    key_init(sk);

    for (int tt = 0; tt < 4; ++tt) {
        const int t = (tt + w) & 3;            // stagger: waves desynchronized
        const int jt = js * 256 + t * 64;
        const size_t jb0 = ((size_t)(b * 256 + (jt >> 4))) * 2048;  // + Y*2048
        f32x4 a0 = {0.f, 0.f, 0.f, 0.f}, a1 = a0, a2 = a0, a3 = a0;

#pragma unroll
        for (int ch = 0; ch < 4; ++ch) {       // K chunks of 32; no barriers
            const int koff = (ch * 4 + l4) * 128 + l15 * 8;   // shorts, 1KiB/wave
            const bf16x8 ih = *(const bf16x8*)(xh + ib0 + koff);
            const bf16x8 im = *(const bf16x8*)(xm + ib0 + koff);
            const bf16x8 il = *(const bf16x8*)(xl + ib0 + koff);
#define DO_Y(ACC, Y)                                                          \
            {                                                                 \
                const bf16x8 jh = *(const bf16x8*)(xh + jb0 + (Y) * 2048 + koff); \
                const bf16x8 jm = *(const bf16x8*)(xm + jb0 + (Y) * 2048 + koff); \
                const bf16x8 jl = *(const bf16x8*)(xl + jb0 + (Y) * 2048 + koff); \
                ACC = __builtin_amdgcn_mfma_f32_16x16x32_bf16(jh, ih, ACC, 0, 0, 0); \
                ACC = __builtin_amdgcn_mfma_f32_16x16x32_bf16(jh, im, ACC, 0, 0, 0); \
                ACC = __builtin_amdgcn_mfma_f32_16x16x32_bf16(jm, ih, ACC, 0, 0, 0); \
                ACC = __builtin_amdgcn_mfma_f32_16x16x32_bf16(jm, im, ACC, 0, 0, 0); \
                ACC = __builtin_amdgcn_mfma_f32_16x16x32_bf16(jh, il, ACC, 0, 0, 0); \
                ACC = __builtin_amdgcn_mfma_f32_16x16x32_bf16(jl, ih, ACC, 0, 0, 0); \
            }
            DO_Y(a0, 0) DO_Y(a1, 1) DO_Y(a2, 2) DO_Y(a3, 3)
#undef DO_Y
        }
        // register-resident scan: lane's j = jt + Y*16 + l4*4 + reg
#define SCAN_Y(ACC, Y)                                                        \
        {                                                                     \
            const int jb4 = jt + (Y) * 16 + l4 * 4;                           \
            const float4 sq4 = *(const float4*)&sqv[b * 4096 + jb4];          \
            key_insert(sk, make_key(fmaf(2.0f, ACC[0], -sq4.x), jb4 + 0));    \
            key_insert(sk, make_key(fmaf(2.0f, ACC[1], -sq4.y), jb4 + 1));    \
            key_insert(sk, make_key(fmaf(2.0f, ACC[2], -sq4.z), jb4 + 2));    \
            key_insert(sk, make_key(fmaf(2.0f, ACC[3], -sq4.w), jb4 + 3));    \
        }
        SCAN_Y(a0, 0) SCAN_Y(a1, 1) SCAN_Y(a2, 2) SCAN_Y(a3, 3)
#undef SCAN_Y
    }
    // merge: i-row (w*16 + l15) has 4 disjoint-j lists at lanes {l15 + 16*l4}
#pragma unroll
    for (int k = 0; k < 9; ++k) MK[tid * 9 + k] = sk[k];
    __syncthreads();
    if (tid < 64) {                            // i = i0 + tid
        u64 mk[9];
        key_init(mk);
        const int wsrc = tid >> 4, r = tid & 15;
        for (int q2 = 0; q2 < 4; ++q2) {
            const int src = wsrc * 64 + q2 * 16 + r;
            for (int k = 0; k < 9; ++k) key_insert(mk, MK[src * 9 + k]);
        }
        // compress: 9 mono-scores + 9 x 8-bit local-j in 3 words (exact)
        u32 ow[12];
        u32 iw0 = 0, iw1 = 0, iw2 = 0;
#pragma unroll
        for (int k = 0; k < 9; ++k) {
            ow[k] = (u32)(mk[k] >> 12);
            u32 lj = (u32)((4095 - (int)(mk[k] & 4095)) - js * 256) & 255u;
            if (k < 4)      iw0 |= lj << (k * 8);
            else if (k < 8) iw1 |= lj << ((k - 4) * 8);
            else            iw2 |= lj;
        }
        ow[9] = iw0; ow[10] = iw1; ow[11] = iw2;
        const size_t base = ((size_t)(b * 4096 + i0 + tid) * NSPLIT + js) * 12;
        *(uint4*)&pk[base]     = *(const uint4*)&ow[0];
        *(uint4*)&pk[base + 4] = *(const uint4*)&ow[4];
        *(uint4*)&pk[base + 8] = *(const uint4*)&ow[8];
    }
}

// ---- Kernel M: merge 16 split-lists -> final 9 indices per row ----
__global__ __launch_bounds__(64) void merge_kernel(const u32* __restrict__ pk,
                                                   int* __restrict__ nn) {
    int t = blockIdx.x * 64 + threadIdx.x;     // grid 128 x 64 = 8192 rows
    u64 mk[9];
    key_init(mk);
    for (int s = 0; s < NSPLIT; ++s) {
        const u32* p = pk + ((size_t)t * NSPLIT + s) * 12;
        u32 ow[12];
        *(uint4*)&ow[0] = *(const uint4*)&p[0];
        *(uint4*)&ow[4] = *(const uint4*)&p[4];
        *(uint4*)&ow[8] = *(const uint4*)&p[8];
        const u32 iw[3] = {ow[9], ow[10], ow[11]};
#pragma unroll
        for (int k = 0; k < 9; ++k) {
            const int lj = (int)((iw[k >> 2] >> ((k & 3) * 8)) & 255u);
            const int jg = s * 256 + lj;
            const u64 key = ((u64)ow[k] << 12) | (u32)(4095 - jg);  // exact reconstruct
            key_insert(mk, key);
        }
    }
#pragma unroll
    for (int k = 0; k < 9; ++k) nn[t * 9 + k] = 4095 - (int)(mk[k] & 4095);
}

// ---- Kernel C: P/Q GEMM on RAW x (reference features are unnormalized;
// the old xn*rn path just reconstructed x with extra rounding). fp32 VALU. ----
__global__ __launch_bounds__(256, 2) void pq_kernel(const float* __restrict__ x,
                                                    const float* __restrict__ wt,
                                                    float* __restrict__ q,
                                                    float* __restrict__ out) {
    __shared__ float Xs[128][64];
    __shared__ float Ws[128][64];
    const int b = blockIdx.z;
    const int n0 = blockIdx.x * 64;
    const int o0 = blockIdx.y * 64;
    const int tid = threadIdx.x;
    {
        const int c4 = tid >> 4, j4 = (tid & 15) * 4;
#pragma unroll
        for (int cc = 0; cc < 8; ++cc) {
            int c = cc * 16 + c4;
            *(float4*)&Xs[c][j4] = *(const float4*)&x[((size_t)(b * 128 + c)) * 4096 + n0 + j4];
            *(float4*)&Ws[c][j4] = *(const float4*)&wt[c * 512 + o0 + j4];
        }
    }
    __syncthreads();
    const int tx = tid & 15, ty = tid >> 4;
    float acc[4][4];
#pragma unroll
    for (int i = 0; i < 4; ++i)
#pragma unroll
        for (int j = 0; j < 4; ++j) acc[i][j] = 0.f;
#pragma unroll 4
    for (int c = 0; c < 128; ++c) {
        const float4 av = *(const float4*)&Xs[c][ty * 4];
        const float4 bv = *(const float4*)&Ws[c][tx * 4];
        const float ar[4] = {av.x, av.y, av.z, av.w};
        const float br[4] = {bv.x, bv.y, bv.z, bv.w};
#pragma unroll
        for (int i = 0; i < 4; ++i)
#pragma unroll
            for (int j = 0; j < 4; ++j) acc[i][j] = fmaf(ar[i], br[j], acc[i][j]);
    }
    if (o0 < 256) {
        // P -> d_out[b][o][n], float4 along n
#pragma unroll
        for (int j = 0; j < 4; ++j) {
            float4 v = make_float4(acc[0][j], acc[1][j], acc[2][j], acc[3][j]);
            *(float4*)&out[((size_t)(b * 256 + o0 + tx * 4 + j)) * 4096 + n0 + ty * 4] = v;
        }
    } else {
#pragma unroll
        for (int i = 0; i < 4; ++i) {
            float4 v = make_float4(acc[i][0], acc[i][1], acc[i][2], acc[i][3]);
            *(float4*)&q[((size_t)(b * 4096 + n0 + ty * 4 + i)) * 256 + (o0 - 256) + tx * 4] = v;
        }
    }
}

// ---- Kernel D: out = relu(P(out) + bias + max_k Q[nn]) in place ----
__global__ __launch_bounds__(256) void gather_kernel(const float* __restrict__ q,
                                                     const int* __restrict__ nn,
                                                     const float* __restrict__ bias,
                                                     float* __restrict__ out) {
    __shared__ int idx[32][9];
    const int b = blockIdx.y, n0 = blockIdx.x * 32;
    const int tid = threadIdx.x;
    for (int t = tid; t < 288; t += 256) {
        int pt = t / 9, k = t - pt * 9;
        idx[pt][k] = nn[(b * 4096 + n0 + pt) * 9 + k];
    }
    __syncthreads();
    const float bv = bias[tid];
    const size_t orow = ((size_t)(b * 256 + tid)) * 4096 + n0;
    float pvals[32];
#pragma unroll
    for (int u = 0; u < 8; ++u)
        *(float4*)&pvals[u * 4] = *(const float4*)&out[orow + u * 4];
    float val[32];
#pragma unroll
    for (int pt = 0; pt < 32; ++pt) {
        float m = -FLT_MAX;
#pragma unroll
        for (int k = 0; k < 9; ++k) {
            int j = idx[pt][k] & 4095;
            m = fmaxf(m, q[((size_t)(b * 4096 + j)) * 256 + tid]);
        }
        float vv = pvals[pt] + bv + m;
        val[pt] = vv > 0.f ? vv : 0.f;
    }
#pragma unroll
    for (int u = 0; u < 8; ++u) {
        float4 v = make_float4(val[u * 4], val[u * 4 + 1], val[u * 4 + 2], val[u * 4 + 3]);
        *(float4*)&out[orow + u * 4] = v;
    }
}

extern "C" void kernel_launch(void* const* d_in, const int* in_sizes, int n_in,
                              void* d_out, int out_size, void* d_ws, size_t ws_size,
                              hipStream_t stream) {
    const float* x    = (const float*)d_in[0];
    const float* w    = (const float*)d_in[1];
    const float* bias = (const float*)d_in[2];
    float* ws = (float*)d_ws;
    float* sq = ws + OFF_SQ;
    float* wt = ws + OFF_WT;
    // RegionA: planes (prep->knn), then Q (pq->gather) — disjoint lifetimes
    unsigned short* xh = (unsigned short*)(ws + OFF_A);
    unsigned short* xm = xh + (size_t)CB * CN * CC;
    unsigned short* xl = xm + (size_t)CB * CN * CC;
    float* q  = ws + OFF_A;
    u32*   pk = (u32*)(ws + OFF_PK);
    int*   nn = (int*)(ws + OFF_NN);
    float* out = (float*)d_out;

    prep_kernel  <<<dim3(64, 2),     256, 0, stream>>>(x, sq, xh, xm, xl);
    wprep_kernel <<<dim3(256),       256, 0, stream>>>(w, wt);
    knn_kernel   <<<dim3(16, 64, 2), 256, 0, stream>>>(xh, xm, xl, sq, pk);
    merge_kernel <<<dim3(128),       64,  0, stream>>>(pk, nn);
    pq_kernel    <<<dim3(64, 8, 2),  256, 0, stream>>>(x, wt, q, out);
    gather_kernel<<<dim3(128, 2),    256, 0, stream>>>(q, nn, bias, out);
}